// Round 11
// baseline (586.087 us; speedup 1.0000x reference)
//
#include <hip/hip_runtime.h>

#define BB 2048
#define IMG 784
#define HWD 28
#define C1 32
#define C2 64
#define PP 169
#define PD 13
#define F3 10816
#define N3 2048
#define K4W 32
#define NOUT 10
#define CONV 27          // pooled-used conv2 output region is 27x27
#define PADW 30          // padded row stride (cols -1..28)
#define OCCHUNK 8
#define OCH 32           // ocs per conv2pool block (2 blocks per sample)
#define SCRS 736         // 729 padded

typedef unsigned long long u64;
typedef int v4i __attribute__((ext_vector_type(4)));

// ap2 magnitude, EXACT: 2^round(log2|c|). round crosses at mantissa sqrt(2).
__device__ __forceinline__ float ap2mag(float c) {
    unsigned int a = __float_as_uint(c) & 0x7fffffffu;
    unsigned int e = (a >> 23) + ((a & 0x7fffffu) > 0x3504f3u);
    return __uint_as_float(e << 23);
}
__device__ __forceinline__ float ap2sgn(float g) {
    unsigned int u = __float_as_uint(g);
    unsigned int a = u & 0x7fffffffu;
    if (a == 0) return 0.f;
    unsigned int e = (a >> 23) + ((a & 0x7fffffu) > 0x3504f3u);
    return __uint_as_float((u & 0x80000000u) | (e << 23));
}

// ---------------- stage0: conv1 mean partials + ALL weight packing ----------------
__global__ __launch_bounds__(256) void stage0(const float* __restrict__ x,
                                              const float* __restrict__ w1, const float* __restrict__ cb1,
                                              float* __restrict__ part1, float* __restrict__ w1b,
                                              const float* __restrict__ w2, unsigned int* __restrict__ w2p,
                                              const float* __restrict__ w3, char* __restrict__ wp3i,
                                              const float* __restrict__ w4, u64* __restrict__ wp4) {
    __shared__ float xs[30 * PADW];
    __shared__ float red[4 * C1];
    int n = blockIdx.x, tid = threadIdx.x;
    int lane = tid & 63, wv = tid >> 6;
    // w3 -> i8 (grid-stride over float4 groups)
    {
        int idx = n * 256 + tid;
        int nthr = gridDim.x * 256;
        int total = (N3 * F3) / 4;
        for (int t = idx; t < total; t += nthr) {
            float4 wv4 = *(const float4*)(w3 + (size_t)t * 4);
            unsigned int w = (wv4.x >= 0.f ? 0x01u : 0xffu)
                           | (wv4.y >= 0.f ? 0x01u : 0xffu) << 8
                           | (wv4.z >= 0.f ? 0x01u : 0xffu) << 16
                           | (wv4.w >= 0.f ? 0x01u : 0xffu) << 24;
            *(unsigned int*)(wp3i + (size_t)t * 4) = w;
        }
    }
    if (n == 0) {
        for (int i = tid; i < C1 * 9; i += 256) w1b[i] = (w1[i] >= 0.f) ? 1.f : -1.f;
    } else if (n == 1) {
        for (int t = tid; t < C2 * 9; t += 256) {
            int oc = t / 9, k = t % 9;
            unsigned int bits = 0;
            for (int ic = 0; ic < C1; ic++)
                bits |= (w2[oc * 288 + ic * 9 + k] >= 0.f ? 1u : 0u) << ic;
            w2p[t] = bits;
        }
    } else if (n == 2) {
        for (int w = wv; w < NOUT * K4W; w += 4) {
            int o = w / K4W, j = w % K4W;
            float wvl = w4[o * N3 + j * 64 + lane];
            u64 mask = __ballot(wvl >= 0.f);
            if (lane == 0) wp4[w] = mask;
        }
    }
    // conv1 pass0 (mean partials)
    for (int i = tid; i < 30 * PADW; i += 256) {
        int r = i / PADW - 1, c = i % PADW - 1;
        float v = 0.f;
        if (r >= 0 && r < HWD && c >= 0 && c < HWD) v = x[n * IMG + r * HWD + c];
        xs[i] = v;
    }
    __syncthreads();
    bool act = tid < 196;
    int r = tid / 7, c0 = (tid % 7) * 4;
    float win[18];
#pragma unroll
    for (int k = 0; k < 18; k++) win[k] = 0.f;
    if (act) {
#pragma unroll
        for (int ry = 0; ry < 3; ry++)
#pragma unroll
            for (int cx = 0; cx < 6; cx++)
                win[ry * 6 + cx] = xs[(r + ry) * PADW + c0 + cx];
    }
#pragma unroll
    for (int ch = 0; ch < C1; ch++) {
        float a = 0.f;
        if (act) {
            float k0 = (w1[ch * 9 + 0] >= 0.f) ? 1.f : -1.f, k1 = (w1[ch * 9 + 1] >= 0.f) ? 1.f : -1.f;
            float k2 = (w1[ch * 9 + 2] >= 0.f) ? 1.f : -1.f, k3 = (w1[ch * 9 + 3] >= 0.f) ? 1.f : -1.f;
            float k4 = (w1[ch * 9 + 4] >= 0.f) ? 1.f : -1.f, k5 = (w1[ch * 9 + 5] >= 0.f) ? 1.f : -1.f;
            float k6 = (w1[ch * 9 + 6] >= 0.f) ? 1.f : -1.f, k7 = (w1[ch * 9 + 7] >= 0.f) ? 1.f : -1.f;
            float k8 = (w1[ch * 9 + 8] >= 0.f) ? 1.f : -1.f;
            float b = cb1[ch];
#pragma unroll
            for (int px = 0; px < 4; px++) {
                float s = win[px] * k0 + win[px + 1] * k1 + win[px + 2] * k2
                        + win[6 + px] * k3 + win[7 + px] * k4 + win[8 + px] * k5
                        + win[12 + px] * k6 + win[13 + px] * k7 + win[14 + px] * k8;
                a += fmaxf(s + b, 0.f);
            }
        }
        for (int off = 32; off; off >>= 1) a += __shfl_down(a, off);
        if (lane == 0) red[wv * C1 + ch] = a;
    }
    __syncthreads();
    if (tid < C1) part1[n * C1 + tid] = red[tid] + red[C1 + tid] + red[2 * C1 + tid] + red[3 * C1 + tid];
}

// ---------------- conv1 var partials ----------------
__global__ __launch_bounds__(256) void conv1_var(const float* __restrict__ x,
                            const float* __restrict__ w1b,
                            const float* __restrict__ cb1, const float* __restrict__ mean1,
                            float* __restrict__ part) {
    __shared__ float xs[30 * PADW];
    __shared__ float red[4 * C1];
    int n = blockIdx.x, tid = threadIdx.x;
    for (int i = tid; i < 30 * PADW; i += 256) {
        int r = i / PADW - 1, c = i % PADW - 1;
        float v = 0.f;
        if (r >= 0 && r < HWD && c >= 0 && c < HWD) v = x[n * IMG + r * HWD + c];
        xs[i] = v;
    }
    __syncthreads();
    bool act = tid < 196;
    int r = tid / 7, c0 = (tid % 7) * 4;
    float win[18];
#pragma unroll
    for (int k = 0; k < 18; k++) win[k] = 0.f;
    if (act) {
#pragma unroll
        for (int ry = 0; ry < 3; ry++)
#pragma unroll
            for (int cx = 0; cx < 6; cx++)
                win[ry * 6 + cx] = xs[(r + ry) * PADW + c0 + cx];
    }
    int lane = tid & 63, wv = tid >> 6;
#pragma unroll
    for (int ch = 0; ch < C1; ch++) {
        float a = 0.f;
        if (act) {
            float k0 = w1b[ch * 9 + 0], k1 = w1b[ch * 9 + 1], k2 = w1b[ch * 9 + 2];
            float k3 = w1b[ch * 9 + 3], k4 = w1b[ch * 9 + 4], k5 = w1b[ch * 9 + 5];
            float k6 = w1b[ch * 9 + 6], k7 = w1b[ch * 9 + 7], k8 = w1b[ch * 9 + 8];
            float b = cb1[ch], m = mean1[ch];
#pragma unroll
            for (int px = 0; px < 4; px++) {
                float s = win[px] * k0 + win[px + 1] * k1 + win[px + 2] * k2
                        + win[6 + px] * k3 + win[7 + px] * k4 + win[8 + px] * k5
                        + win[12 + px] * k6 + win[13 + px] * k7 + win[14 + px] * k8;
                float v = fmaxf(s + b, 0.f);
                float c = v - m;
                a += fabsf(c) * ap2mag(c);
            }
        }
        for (int off = 32; off; off >>= 1) a += __shfl_down(a, off);
        if (lane == 0) red[wv * C1 + ch] = a;
    }
    __syncthreads();
    if (tid < C1) part[n * C1 + tid] = red[tid] + red[C1 + tid] + red[2 * C1 + tid] + red[3 * C1 + tid];
}

// binarize(shift_bn(relu(conv1))) -> 32 channel bits per pixel, aligned uint4 store.
__global__ __launch_bounds__(256) void conv1_pack(const float* __restrict__ x,
                           const float* __restrict__ w1b,
                           const float* __restrict__ cb1, const float* __restrict__ mean1,
                           const float* __restrict__ scale1, const float* __restrict__ beta1,
                           unsigned int* __restrict__ s1p) {
    __shared__ float xs[30 * PADW];
    int n = blockIdx.x, tid = threadIdx.x;
    for (int i = tid; i < 30 * PADW; i += 256) {
        int r = i / PADW - 1, c = i % PADW - 1;
        float v = 0.f;
        if (r >= 0 && r < HWD && c >= 0 && c < HWD) v = x[n * IMG + r * HWD + c];
        xs[i] = v;
    }
    __syncthreads();
    if (tid >= 196) return;
    int r = tid / 7, c0 = (tid % 7) * 4;
    float win[18];
#pragma unroll
    for (int ry = 0; ry < 3; ry++)
#pragma unroll
        for (int cx = 0; cx < 6; cx++)
            win[ry * 6 + cx] = xs[(r + ry) * PADW + c0 + cx];
    unsigned int bits0 = 0, bits1 = 0, bits2 = 0, bits3 = 0;
#pragma unroll
    for (int ch = 0; ch < C1; ch++) {
        float k0 = w1b[ch * 9 + 0], k1 = w1b[ch * 9 + 1], k2 = w1b[ch * 9 + 2];
        float k3 = w1b[ch * 9 + 3], k4 = w1b[ch * 9 + 4], k5 = w1b[ch * 9 + 5];
        float k6 = w1b[ch * 9 + 6], k7 = w1b[ch * 9 + 7], k8 = w1b[ch * 9 + 8];
        float b = cb1[ch], m = mean1[ch], sc = scale1[ch], bt = beta1[ch];
#pragma unroll
        for (int px = 0; px < 4; px++) {
            float s = win[px] * k0 + win[px + 1] * k1 + win[px + 2] * k2
                    + win[6 + px] * k3 + win[7 + px] * k4 + win[8 + px] * k5
                    + win[12 + px] * k6 + win[13 + px] * k7 + win[14 + px] * k8;
            float v = fmaxf(s + b, 0.f);
            float val = sc * (v - m) + bt;
            unsigned int bit = (val >= 0.f ? 1u : 0u) << ch;
            if (px == 0) bits0 |= bit;
            else if (px == 1) bits1 |= bit;
            else if (px == 2) bits2 |= bit;
            else bits3 |= bit;
        }
    }
    uint4 w4v = make_uint4(bits0, bits1, bits2, bits3);
    *reinterpret_cast<uint4*>(&s1p[n * IMG + r * HWD + c0]) = w4v;  // 16B aligned
}

// ---------------- conv2 + maxpool3s2 + mean partials, 2 blocks/sample ----------------
__global__ __launch_bounds__(256) void conv2pool(const unsigned int* __restrict__ s1p,
                                                 const unsigned int* __restrict__ w2p,
                                                 const float* __restrict__ cb2,
                                                 short* __restrict__ p2i,
                                                 float* __restrict__ part2) {
    __shared__ unsigned int spad[29 * PADW];   // 3.5 KB
    __shared__ short scr[OCCHUNK * SCRS];      // 11.8 KB
    __shared__ float psum[OCCHUNK * PP];       // 5.4 KB
    __shared__ float pm[OCH];
    int n = blockIdx.x, ocb = blockIdx.y * OCH, tid = threadIdx.x;
    for (int i = tid; i < 29 * PADW; i += 256) {
        int r = i / PADW, c = i - r * PADW;
        unsigned int v = 0;
        if (r >= 1 && c >= 1 && c <= 28) v = s1p[n * IMG + (r - 1) * HWD + (c - 1)];
        spad[i] = v;
    }
    __syncthreads();
    unsigned int win[3][9];
    bool top_[3], left_[3];
    bool act2 = (tid + 512) < CONV * CONV;
#pragma unroll
    for (int pi = 0; pi < 3; pi++) {
        int p = tid + pi * 256;
        if (p >= CONV * CONV) p = 0;
        int y = p / CONV, xx = p - y * CONV;
        top_[pi] = (y == 0);
        left_[pi] = (xx == 0);
        const unsigned int* bp = &spad[y * PADW + xx];
#pragma unroll
        for (int ky = 0; ky < 3; ky++)
#pragma unroll
            for (int kx = 0; kx < 3; kx++)
                win[pi][ky * 3 + kx] = bp[ky * PADW + kx];
    }
    int lane = tid & 63, wv = tid >> 6;
    for (int base = 0; base < OCH; base += OCCHUNK) {
        for (int ol = 0; ol < OCCHUNK; ol++) {
            int oc = ocb + base + ol;
            unsigned int w0 = w2p[oc * 9 + 0], w1 = w2p[oc * 9 + 1], w2 = w2p[oc * 9 + 2];
            unsigned int w3 = w2p[oc * 9 + 3], w4 = w2p[oc * 9 + 4], w5 = w2p[oc * 9 + 5];
            unsigned int w6 = w2p[oc * 9 + 6], w7 = w2p[oc * 9 + 7], w8 = w2p[oc * 9 + 8];
            int p0 = __popc(w0), p1 = __popc(w1), p2 = __popc(w2);
            int p3 = __popc(w3), p6 = __popc(w6);
            int ct = 192 + 2 * (p0 + p1 + p2);
            int cl = 192 + 2 * (p0 + p3 + p6);
            int cc = 128 + 2 * (p0 + p1 + p2 + p3 + p6);
#pragma unroll
            for (int pi = 0; pi < 3; pi++) {
                int s = __popc(win[pi][0] ^ w0) + __popc(win[pi][1] ^ w1) + __popc(win[pi][2] ^ w2)
                      + __popc(win[pi][3] ^ w3) + __popc(win[pi][4] ^ w4) + __popc(win[pi][5] ^ w5)
                      + __popc(win[pi][6] ^ w6) + __popc(win[pi][7] ^ w7) + __popc(win[pi][8] ^ w8);
                int off = top_[pi] ? (left_[pi] ? cc : ct) : (left_[pi] ? cl : 288);
                if (pi < 2 || act2) scr[ol * SCRS + tid + pi * 256] = (short)(off - 2 * s);
            }
        }
        __syncthreads();
        for (int q = tid; q < OCCHUNK * PP; q += 256) {
            int ol = q / PP, pix = q - ol * PP;
            int py = pix / PD, px = pix - py * PD;
            const short* rr = &scr[ol * SCRS + (2 * py) * CONV + 2 * px];
            int m0 = max(max((int)rr[0], (int)rr[1]), (int)rr[2]);
            int m1 = max(max((int)rr[CONV], (int)rr[CONV + 1]), (int)rr[CONV + 2]);
            int m2 = max(max((int)rr[2 * CONV], (int)rr[2 * CONV + 1]), (int)rr[2 * CONV + 2]);
            int val = max(max(m0, m1), m2);
            p2i[n * F3 + (ocb + base + ol) * PP + pix] = (short)val;
            psum[q] = fmaxf((float)val + cb2[ocb + base + ol], 0.f);
        }
        __syncthreads();
        for (int ol = wv; ol < OCCHUNK; ol += 4) {
            float a = 0.f;
            for (int p = lane; p < PP; p += 64) a += psum[ol * PP + p];
            for (int off = 32; off; off >>= 1) a += __shfl_down(a, off);
            if (lane == 0) pm[base + ol] = a;
        }
        __syncthreads();
    }
    if (tid < OCH) part2[n * C2 + ocb + tid] = pm[tid];
}

// ---------------- p2 var partials ----------------
__global__ __launch_bounds__(256) void p2_var(const short* __restrict__ p2i,
                         const float* __restrict__ cb2,
                         const float* __restrict__ mean2, float* __restrict__ part) {
    int n = blockIdx.x, tid = threadIdx.x, lane = tid & 63, wv = tid >> 6;
    const short* rowb = p2i + (size_t)n * F3;
    __shared__ float red[C2];
#pragma unroll
    for (int i = 0; i < 16; i++) {
        int ch = wv * 16 + i;
        const short* row = rowb + ch * PP;
        float b = cb2[ch];
        float m = mean2[ch];
        float a = 0.f;
        for (int p = lane; p < PP; p += 64) {
            float v = fmaxf((float)row[p] + b, 0.f);
            float c = v - m;
            a += fabsf(c) * ap2mag(c);
        }
        for (int off = 32; off; off >>= 1) a += __shfl_down(a, off);
        if (lane == 0) red[ch] = a;
    }
    __syncthreads();
    if (tid < C2) part[n * C2 + tid] = red[tid];
}

// ---------------- stage-2 reduce: mean or ap2-scale ----------------
__global__ __launch_bounds__(256) void reduce_stats(const float* __restrict__ part, int nch, int nblk,
                             const float* __restrict__ g, float* __restrict__ outv,
                             int mode, double count) {
    int ch = blockIdx.x, tid = threadIdx.x;
    double a = 0.0;
    for (int i = tid; i < nblk; i += 256) a += (double)part[(size_t)i * nch + ch];
    __shared__ double red[4];
    for (int off = 32; off; off >>= 1) a += __shfl_down(a, off);
    int lane = tid & 63, wv = tid >> 6;
    if (lane == 0) red[wv] = a;
    __syncthreads();
    if (tid == 0) {
        double s = red[0] + red[1] + red[2] + red[3];
        if (mode == 0) {
            outv[ch] = (float)(s / count);
        } else {
            float var = (float)(s / count);
            float inv = 1.0f / sqrtf(var + 1e-4f);
            outv[ch] = ap2sgn(g[ch]) * ap2mag(inv);
        }
    }
}

// binarize layer-2 -> i8 (+1/-1) plane [BB][F3] for MFMA lin3
__global__ __launch_bounds__(256) void p2_packi8(const short* __restrict__ p2i, const float* __restrict__ cb2,
                        const float* __restrict__ mean2, const float* __restrict__ scale2,
                        const float* __restrict__ beta2, char* __restrict__ hp3i) {
    int idx = blockIdx.x * 256 + threadIdx.x;
    int nthr = gridDim.x * 256;
    int total = (BB * F3) / 4;
    for (int t = idx; t < total; t += nthr) {
        int base = t * 4;
        int f0 = base % F3;
        unsigned int w = 0;
#pragma unroll
        for (int e = 0; e < 4; e++) {
            int f = f0 + e;
            int oc = f / PP;
            float v = fmaxf((float)p2i[base + e] + cb2[oc], 0.f);
            float val = scale2[oc] * (v - mean2[oc]) + beta2[oc];
            w |= (val >= 0.f ? 0x01u : 0xffu) << (8 * e);
        }
        *(unsigned int*)(hp3i + base) = w;
    }
}

// ---------------- lin3: i8 MFMA GEMM, 128x64 block tile, 512 threads ----------------
// R10 post-mortem: 64x32 wave tiles cap the GEMM at 2048 waves = 2 waves/SIMD;
// load latency (200-900cy) >> per-SIMD MFMA window (78cy) -> MfmaUtil 16%.
// Fix: 32x32 wave tiles, 8 waves/block (512 thr) -> 4096 waves = 4 waves/SIMD,
// 4-way wave interleave hides the prefetch latency (m114 co-scheduling).
// Same fragment mappings as R9/R10 (two passing rounds): k-permutation cancels
// (identical A/B layout), C/D col=lane&15 row=(lane>>4)*4+reg.
__global__ __launch_bounds__(512) void lin3_mfma(const char* __restrict__ hp3i,
                                                 const char* __restrict__ wp3i,
                                                 const float* __restrict__ b3l,
                                                 float* __restrict__ h3,
                                                 float* __restrict__ part3) {
    __shared__ v4i aL[2][512];   // 2 bufs x (8 rowgroups x 64 lane-frags) = 16 KB
    __shared__ v4i bL[2][256];   // 2 bufs x (4 rowgroups x 64) = 8 KB
    __shared__ float csr[8][32];
    int tid = threadIdx.x;
    int lane = tid & 63, wv = tid >> 6;      // 8 waves
    int wr = wv >> 1, wc = wv & 1;           // 4x2 wave grid, wave tile 32x32
    int m0 = blockIdx.y * 128, n0 = blockIdx.x * 64;
    // A staging: thread t (0..511) owns row ra = t>>2, 16B quarter qa = t&3
    int ra = tid >> 2, qa = tid & 3;
    const char* ag = hp3i + (size_t)(m0 + ra) * F3 + qa * 16;
    int abase = (ra >> 4) * 64 + qa * 16 + (ra & 15);
    // B staging: threads 0..255 own row rb = t>>2, quarter qb = t&3
    const char* bg = wp3i + (size_t)(n0 + ra) * F3 + qa * 16;  // ra<64 for tid<256
    int bbase = abase;                                          // same formula
    bool doB = tid < 256;
    v4i acc[2][2];
#pragma unroll
    for (int i = 0; i < 2; i++)
#pragma unroll
        for (int j = 0; j < 2; j++) acc[i][j] = (v4i){0, 0, 0, 0};
    // preload chunk 0 into buf 0
    v4i a0 = *(const v4i*)ag;
    v4i b0 = doB ? *(const v4i*)bg : (v4i){0, 0, 0, 0};
    aL[0][abase] = a0;
    if (doB) bL[0][bbase] = b0;
    __syncthreads();
    for (int c = 0; c < 169; c++) {
        int cur = c & 1, nxt = cur ^ 1;
        if (c < 168) {  // issue prefetch of next chunk (overlaps MFMA below)
            ag += 64;
            a0 = *(const v4i*)ag;
            if (doB) { bg += 64; b0 = *(const v4i*)bg; }
        }
        v4i af[2], bf[2];
#pragma unroll
        for (int i = 0; i < 2; i++) af[i] = aL[cur][(wr * 2 + i) * 64 + lane];
#pragma unroll
        for (int j = 0; j < 2; j++) bf[j] = bL[cur][(wc * 2 + j) * 64 + lane];
#pragma unroll
        for (int i = 0; i < 2; i++)
#pragma unroll
            for (int j = 0; j < 2; j++)
                acc[i][j] = __builtin_amdgcn_mfma_i32_16x16x64_i8(af[i], bf[j], acc[i][j], 0, 0, 0);
        if (c < 168) {  // store prefetch into the other buffer
            aL[nxt][abase] = a0;
            if (doB) bL[nxt][bbase] = b0;
        }
        __syncthreads();
    }
    int q = lane >> 4, m16 = lane & 15;
    float cs[2] = {0.f, 0.f};
#pragma unroll
    for (int j = 0; j < 2; j++) {
        int col = n0 + wc * 32 + j * 16 + m16;
        float bias = b3l[col];
#pragma unroll
        for (int i = 0; i < 2; i++) {
            int rowb = m0 + wr * 32 + i * 16 + q * 4;
#pragma unroll
            for (int rg = 0; rg < 4; rg++) {
                float v = fmaxf((float)acc[i][j][rg] + bias, 0.f);
                h3[(size_t)(rowb + rg) * N3 + col] = v;
                cs[j] += v;
            }
        }
    }
#pragma unroll
    for (int j = 0; j < 2; j++) {
        cs[j] += __shfl_xor(cs[j], 16);
        cs[j] += __shfl_xor(cs[j], 32);
        if (lane < 16) csr[wv][j * 16 + m16] = cs[j];
    }
    __syncthreads();
    if (tid < 64) {
        int cg = tid >> 5, cc = tid & 31;   // block-local column c = tid
        part3[(size_t)blockIdx.y * N3 + n0 + tid] =
            csr[cg][cc] + csr[2 + cg][cc] + csr[4 + cg][cc] + csr[6 + cg][cc];
    }
}

// ---------------- h3: mean + var + scale, one kernel per column ----------------
__global__ __launch_bounds__(256) void h3_finish(const float* __restrict__ h3,
                                                 const float* __restrict__ part3,
                                                 const float* __restrict__ g3,
                                                 float* __restrict__ mean3, float* __restrict__ scale3) {
    int nn = blockIdx.x, tid = threadIdx.x;
    __shared__ float msh;
    __shared__ double redd[4];
    if (tid < 64) {
        float a = (tid < 16) ? part3[(size_t)tid * N3 + nn] : 0.f;
        for (int off = 8; off; off >>= 1) a += __shfl_down(a, off);
        if (tid == 0) { float m = a / (float)BB; mean3[nn] = m; msh = m; }
    }
    __syncthreads();
    float m = msh;
    float acc = 0.f;
#pragma unroll
    for (int q = 0; q < 8; q++) {
        float v = h3[(size_t)(q * 256 + tid) * N3 + nn];
        float c = v - m;
        acc += fabsf(c) * ap2mag(c);
    }
    double a = (double)acc;
    for (int off = 32; off; off >>= 1) a += __shfl_down(a, off);
    int lane = tid & 63, wv = tid >> 6;
    if (lane == 0) redd[wv] = a;
    __syncthreads();
    if (tid == 0) {
        float var = (float)((redd[0] + redd[1] + redd[2] + redd[3]) / (double)BB);
        float inv = 1.0f / sqrtf(var + 1e-4f);
        scale3[nn] = ap2sgn(g3[nn]) * ap2mag(inv);
    }
}

// ---------------- fused h3 binarize + lin4 (one block per sample) ----------------
__global__ __launch_bounds__(256) void h4_out(const float* __restrict__ h3,
                                              const float* __restrict__ mean3, const float* __restrict__ scale3,
                                              const float* __restrict__ bt3,
                                              const u64* __restrict__ wp4, const float* __restrict__ b4,
                                              float* __restrict__ out) {
    __shared__ u64 hb[K4W];
    __shared__ u64 wsh[NOUT * 33];
    int m = blockIdx.x, tid = threadIdx.x, lane = tid & 63, wv = tid >> 6;
    for (int i = tid; i < NOUT * K4W; i += 256) wsh[(i / K4W) * 33 + (i % K4W)] = wp4[i];
#pragma unroll
    for (int q = 0; q < 8; q++) {
        int j = wv * 8 + q;
        int f = j * 64 + lane;
        float v = h3[(size_t)m * N3 + f];
        float val = scale3[f] * (v - mean3[f]) + bt3[f];
        u64 mask = __ballot(val >= 0.f);
        if (lane == 0) hb[j] = mask;
    }
    __syncthreads();
    if (tid < NOUT) {
        int c = 0;
#pragma unroll
        for (int k = 0; k < K4W; k++) c += (int)__popcll(hb[k] ^ wsh[tid * 33 + k]);
        out[m * NOUT + tid] = (float)(N3 - 2 * c) + b4[tid];
    }
}

extern "C" void kernel_launch(void* const* d_in, const int* in_sizes, int n_in,
                              void* d_out, int out_size, void* d_ws, size_t ws_size,
                              hipStream_t stream) {
    const float* x   = (const float*)d_in[0];
    const float* w1  = (const float*)d_in[1];
    const float* cb1 = (const float*)d_in[2];
    const float* g1  = (const float*)d_in[3];
    const float* bt1 = (const float*)d_in[4];
    const float* w2  = (const float*)d_in[5];
    const float* cb2 = (const float*)d_in[6];
    const float* g2  = (const float*)d_in[7];
    const float* bt2 = (const float*)d_in[8];
    const float* w3  = (const float*)d_in[9];
    const float* b3l = (const float*)d_in[10];
    const float* g3  = (const float*)d_in[11];
    const float* bt3 = (const float*)d_in[12];
    const float* w4  = (const float*)d_in[13];
    const float* b4l = (const float*)d_in[14];
    float* out = (float*)d_out;

    char* base = (char*)d_ws;
    size_t off = 0;
    auto carve = [&](size_t bytes) { char* p = base + off; off = (off + bytes + 255) & ~(size_t)255; return p; };
    // lifetime-aliased buffers:
    char* bufA = carve((size_t)BB * C2 * PP * 2);   // p2i (44.3 MB); h3 aliases (dead after p2_packi8)
    char* bufB = carve((size_t)BB * F3);            // hp3i (22.2 MB); s1p aliases (dead before p2_packi8)
    char* bufC = carve((size_t)N3 * F3);            // wp3i (22.2 MB)
    short* p2i         = (short*)bufA;
    float* h3          = (float*)bufA;
    char* hp3i         = bufB;
    unsigned int* s1p  = (unsigned int*)bufB;
    char* wp3i         = bufC;
    u64* wp4           = (u64*)carve((size_t)NOUT * K4W * 8);
    unsigned int* w2p  = (unsigned int*)carve((size_t)C2 * 9 * 4);
    float* w1b         = (float*)carve((size_t)C1 * 9 * 4);
    float* part1       = (float*)carve((size_t)BB * C1 * 4);
    float* part2       = (float*)carve((size_t)BB * C2 * 4);
    float* part3       = (float*)carve((size_t)16 * N3 * 4);
    float* fstats      = (float*)carve((size_t)(32 + 32 + 64 + 64 + 2048 + 2048) * 4);
    float* mean1 = fstats;          float* scale1 = fstats + 32;
    float* mean2 = fstats + 64;     float* scale2 = fstats + 128;
    float* mean3 = fstats + 192;    float* scale3 = fstats + 2240;

    stage0<<<BB, 256, 0, stream>>>(x, w1, cb1, part1, w1b, w2, w2p, w3, wp3i, w4, wp4);
    reduce_stats<<<C1, 256, 0, stream>>>(part1, C1, BB, g1, mean1, 0, (double)BB * IMG);
    conv1_var<<<BB, 256, 0, stream>>>(x, w1b, cb1, mean1, part1);
    reduce_stats<<<C1, 256, 0, stream>>>(part1, C1, BB, g1, scale1, 1, (double)BB * IMG);
    conv1_pack<<<BB, 256, 0, stream>>>(x, w1b, cb1, mean1, scale1, bt1, s1p);
    conv2pool<<<dim3(BB, 2), 256, 0, stream>>>(s1p, w2p, cb2, p2i, part2);
    reduce_stats<<<C2, 256, 0, stream>>>(part2, C2, BB, g2, mean2, 0, (double)BB * PP);
    p2_var<<<BB, 256, 0, stream>>>(p2i, cb2, mean2, part2);
    reduce_stats<<<C2, 256, 0, stream>>>(part2, C2, BB, g2, scale2, 1, (double)BB * PP);
    p2_packi8<<<2048, 256, 0, stream>>>(p2i, cb2, mean2, scale2, bt2, hp3i);
    lin3_mfma<<<dim3(32, 16), 512, 0, stream>>>(hp3i, wp3i, b3l, h3, part3);
    h3_finish<<<N3, 256, 0, stream>>>(h3, part3, g3, mean3, scale3);
    h4_out<<<BB, 256, 0, stream>>>(h3, mean3, scale3, bt3, wp4, b4l, out);

    (void)in_sizes; (void)n_in; (void)out_size; (void)ws_size;
}